// Round 4
// baseline (440.040 us; speedup 1.0000x reference)
//
#include <hip/hip_runtime.h>

// Problem constants: B=2, N=2048, C=512, H=8, HD=64
// Inputs fp32 (per reference); intermediates bf16 in ws; output fp32.
typedef __attribute__((ext_vector_type(8))) short bf16x8;
typedef __attribute__((ext_vector_type(4))) float f32x4;

__device__ __forceinline__ float bf2f(unsigned short u) {
  union { unsigned int i; float f; } c; c.i = ((unsigned int)u) << 16; return c.f;
}
__device__ __forceinline__ unsigned short f2bf(float x) {
  union { float f; unsigned int i; } c; c.f = x;
  return (unsigned short)((c.i + 0x7fffu + ((c.i >> 16) & 1u)) >> 16);
}

// Load 8 source elements as 8 packed bf16 (one uint4).
template <typename T> __device__ __forceinline__ uint4 ld8(const T* p);
template <> __device__ __forceinline__ uint4 ld8<unsigned short>(const unsigned short* p) {
  return *(const uint4*)p;
}
template <> __device__ __forceinline__ uint4 ld8<float>(const float* p) {
  const float4 a = *(const float4*)p;
  const float4 b = *(const float4*)(p + 4);
  uint4 r;
  r.x = (unsigned)f2bf(a.x) | ((unsigned)f2bf(a.y) << 16);
  r.y = (unsigned)f2bf(a.z) | ((unsigned)f2bf(a.w) << 16);
  r.z = (unsigned)f2bf(b.x) | ((unsigned)f2bf(b.y) << 16);
  r.w = (unsigned)f2bf(b.z) | ((unsigned)f2bf(b.w) << 16);
  return r;
}

// 64x64 output tile, 256 threads (4 waves x 16-row strips), NT GEMM:
// acc[nt][r] = C[m0 + w*16 + lq*4 + r][cc0 + nt*16 + lm]
template <int K, typename TA, typename TW>
__device__ __forceinline__ void gemm_mainloop(const TA* __restrict__ Arow,
                                              const TW* __restrict__ Wrow,
                                              short (*As)[72], short (*Ws)[72], f32x4 acc[4]) {
  const int tid = threadIdx.x;
  const int w = tid >> 6, lane = tid & 63, lm = lane & 15, lq = lane >> 4;
#pragma unroll
  for (int nt = 0; nt < 4; ++nt) acc[nt] = (f32x4){0.f, 0.f, 0.f, 0.f};
#pragma unroll 1
  for (int kc = 0; kc < K; kc += 64) {
    __syncthreads();
#pragma unroll
    for (int s = 0; s < 2; ++s) {
      int u = tid + s * 256, row = u >> 3, c8 = (u & 7) * 8;
      *(uint4*)&As[row][c8] = ld8(&Arow[(size_t)row * K + kc + c8]);
      *(uint4*)&Ws[row][c8] = ld8(&Wrow[(size_t)row * K + kc + c8]);
    }
    __syncthreads();
#pragma unroll
    for (int kk = 0; kk < 64; kk += 32) {
      bf16x8 a = *(const bf16x8*)&As[w * 16 + lm][kk + lq * 8];
#pragma unroll
      for (int nt = 0; nt < 4; ++nt) {
        bf16x8 bb = *(const bf16x8*)&Ws[nt * 16 + lm][kk + lq * 8];
        acc[nt] = __builtin_amdgcn_mfma_f32_16x16x32_bf16(a, bb, acc[nt], 0, 0, 0);
      }
    }
  }
}

// qkv = x @ Wqkv^T; scatter to qu=q+u_bias, qv=q+v_bias, k, v in [B,H,N,HD] (bf16)
__global__ __launch_bounds__(256) void k_gemm_qkv(const float* __restrict__ x,
    const float* __restrict__ wqkv, const float* __restrict__ ub,
    const float* __restrict__ vb, unsigned short* __restrict__ qu,
    unsigned short* __restrict__ qv, unsigned short* __restrict__ kg,
    unsigned short* __restrict__ vg) {
  __shared__ short As[64][72], Ws[64][72];
  f32x4 acc[4];
  const int m0 = blockIdx.y * 64, cc0 = blockIdx.x * 64;
  gemm_mainloop<512>(x + (size_t)m0 * 512, wqkv + (size_t)cc0 * 512, As, Ws, acc);
  const int tid = threadIdx.x, w = tid >> 6, lane = tid & 63, lm = lane & 15, lq = lane >> 4;
#pragma unroll
  for (int nt = 0; nt < 4; ++nt) {
    const int cc = cc0 + nt * 16 + lm;
    const int sec = cc >> 9, rem = cc & 511, h = rem >> 6, d = rem & 63;
#pragma unroll
    for (int r = 0; r < 4; ++r) {
      const int m = m0 + w * 16 + lq * 4 + r;
      const int b = m >> 11, n = m & 2047;
      const size_t idx = ((size_t)(b * 8 + h) * 2048 + n) * 64 + d;
      const float val = acc[nt][r];
      if (sec == 0) {
        qu[idx] = f2bf(val + ub[rem]);
        qv[idx] = f2bf(val + vb[rem]);
      } else if (sec == 1) {
        kg[idx] = f2bf(val);
      } else {
        vg[idx] = f2bf(val);
      }
    }
  }
}

// pos = pos_embedding @ Wpos^T -> [B,H,N,HD] (bf16)
__global__ __launch_bounds__(256) void k_gemm_pos(const float* __restrict__ pe,
    const float* __restrict__ wpos, unsigned short* __restrict__ pos) {
  __shared__ short As[64][72], Ws[64][72];
  f32x4 acc[4];
  const int m0 = blockIdx.y * 64, cc0 = blockIdx.x * 64;
  gemm_mainloop<512>(pe + (size_t)m0 * 512, wpos + (size_t)cc0 * 512, As, Ws, acc);
  const int tid = threadIdx.x, w = tid >> 6, lane = tid & 63, lm = lane & 15, lq = lane >> 4;
#pragma unroll
  for (int nt = 0; nt < 4; ++nt) {
    const int cc = cc0 + nt * 16 + lm, h = cc >> 6, d = cc & 63;
#pragma unroll
    for (int r = 0; r < 4; ++r) {
      const int m = m0 + w * 16 + lq * 4 + r, b = m >> 11, n = m & 2047;
      pos[((size_t)(b * 8 + h) * 2048 + n) * 64 + d] = f2bf(acc[nt][r]);
    }
  }
}

// vt[b,h,d,n] = v[b,h,n,d]
__global__ __launch_bounds__(256) void k_transpose_v(const unsigned short* __restrict__ vg,
                                                     unsigned short* __restrict__ vt) {
  __shared__ short T[64][72];
  const int tid = threadIdx.x, bhid = blockIdx.y, n0 = blockIdx.x * 64;
#pragma unroll
  for (int s = 0; s < 2; ++s) {
    int u = tid + s * 256, row = u >> 3, c8 = (u & 7) * 8;
    *(uint4*)&T[row][c8] = *(const uint4*)&vg[((size_t)bhid * 2048 + n0 + row) * 64 + c8];
  }
  __syncthreads();
#pragma unroll
  for (int s = 0; s < 2; ++s) {
    int u = tid + s * 256, d = u >> 3, n8 = (u & 7) * 8;
    alignas(16) unsigned short tmp[8];
#pragma unroll
    for (int jj = 0; jj < 8; ++jj) tmp[jj] = (unsigned short)T[n8 + jj][d];
    *(uint4*)&vt[((size_t)bhid * 64 + d) * 2048 + n0 + n8] = *(const uint4*)tmp;
  }
}

// ps[bh,i,e] = qv_i . pos_e.  64x256 tile: A staged once, 4 e-subtiles,
// epilogue via same-wave LDS transpose -> uint4 coalesced stores.
__global__ __launch_bounds__(256) void k_gemm_ps(const unsigned short* __restrict__ qv,
    const unsigned short* __restrict__ pos, unsigned short* __restrict__ ps) {
  __shared__ short As[64][72], Ws[64][72], Os[64][72];
  const int tid = threadIdx.x, w = tid >> 6, lane = tid & 63, lm = lane & 15, lq = lane >> 4;
  const int bh = blockIdx.z, i0 = blockIdx.y * 64;
  const unsigned short* Arow = qv + ((size_t)bh * 2048 + i0) * 64;
  const unsigned short* Prow = pos + (size_t)bh * 2048 * 64;
#pragma unroll
  for (int s = 0; s < 2; ++s) {
    int u = tid + s * 256, row = u >> 3, c8 = (u & 7) * 8;
    *(uint4*)&As[row][c8] = *(const uint4*)&Arow[(size_t)row * 64 + c8];
  }
#pragma unroll 1
  for (int et = 0; et < 4; ++et) {
    const int e0 = blockIdx.x * 256 + et * 64;
    __syncthreads();  // guards Ws overwrite (and As stage on first iter)
#pragma unroll
    for (int s = 0; s < 2; ++s) {
      int u = tid + s * 256, row = u >> 3, c8 = (u & 7) * 8;
      *(uint4*)&Ws[row][c8] = *(const uint4*)&Prow[(size_t)(e0 + row) * 64 + c8];
    }
    __syncthreads();
    f32x4 acc[4];
#pragma unroll
    for (int nt = 0; nt < 4; ++nt) acc[nt] = (f32x4){0.f, 0.f, 0.f, 0.f};
#pragma unroll
    for (int kk = 0; kk < 64; kk += 32) {
      bf16x8 a = *(const bf16x8*)&As[w * 16 + lm][kk + lq * 8];
#pragma unroll
      for (int nt = 0; nt < 4; ++nt) {
        bf16x8 bb = *(const bf16x8*)&Ws[nt * 16 + lm][kk + lq * 8];
        acc[nt] = __builtin_amdgcn_mfma_f32_16x16x32_bf16(a, bb, acc[nt], 0, 0, 0);
      }
    }
    // Epilogue: C-layout -> Os (wave w owns rows w*16..w*16+15; same-wave r/w, in-order DS)
#pragma unroll
    for (int nt = 0; nt < 4; ++nt)
#pragma unroll
      for (int r = 0; r < 4; ++r)
        Os[w * 16 + lq * 4 + r][nt * 16 + lm] = (short)f2bf(acc[nt][r]);
    // 4 threads/row, each stores 16 cols (2x uint4) -> full 64 cols covered.
    const int row = tid >> 2, q = tid & 3;  // wave w -> rows w*16..w*16+15
    const size_t orow = ((size_t)bh * 2048 + i0 + row) * 2048 + e0;
    alignas(16) short tmp[8];
    *(uint4*)tmp = *(const uint4*)&Os[row][q * 16];
    *(uint4*)&ps[orow + q * 16] = *(const uint4*)tmp;
    *(uint4*)tmp = *(const uint4*)&Os[row][q * 16 + 8];
    *(uint4*)&ps[orow + q * 16 + 8] = *(const uint4*)tmp;
  }
}

// Flash attention, KV-split: chunk handles j in [chunk*1024, chunk*1024+1024).
// Writes unnormalized O partials (fp32) + per-row (m,l) for the combine pass.
__global__ __launch_bounds__(256) void k_flash(const unsigned short* __restrict__ qu,
    const unsigned short* __restrict__ kg, const unsigned short* __restrict__ vt,
    const unsigned short* __restrict__ ps, float* __restrict__ opart,
    float* __restrict__ ml) {
  __shared__ short Ks[64][72], Vs[64][72], Ps[4][16][72];
  const int tid = threadIdx.x, w = tid >> 6, lane = tid & 63, lm = lane & 15, lq = lane >> 4;
  const int chunk = blockIdx.y, bh = blockIdx.z;
  const int iw = blockIdx.x * 64 + w * 16;
  const size_t bhs = (size_t)bh;
  const bf16x8 au0 = *(const bf16x8*)&qu[(bhs * 2048 + iw + lm) * 64 + lq * 8];
  const bf16x8 au1 = *(const bf16x8*)&qu[(bhs * 2048 + iw + lm) * 64 + 32 + lq * 8];
  const unsigned short* psb = ps + bhs * (size_t)2048 * 2048;
  float m_run[4], l_run[4];
  f32x4 oacc[4];
#pragma unroll
  for (int r = 0; r < 4; ++r) { m_run[r] = -1e30f; l_run[r] = 0.f; }
#pragma unroll
  for (int dt = 0; dt < 4; ++dt) oacc[dt] = (f32x4){0.f, 0.f, 0.f, 0.f};
  const int jbeg = chunk * 1024;
#pragma unroll 1
  for (int j0 = jbeg; j0 < jbeg + 1024; j0 += 64) {
    // Issue K/V loads to regs FIRST, then ps gathers: the staging ds_writes
    // only need vmcnt to cover the older K/V loads, so the 16 gathers stay
    // in flight across staging + QK^T MFMAs.
    uint4 kr[2], vr[2];
#pragma unroll
    for (int s = 0; s < 2; ++s) {
      int u = tid + s * 256, row = u >> 3, c8 = (u & 7) * 8;
      kr[s] = *(const uint4*)&kg[(bhs * 2048 + j0 + row) * 64 + c8];
      vr[s] = *(const uint4*)&vt[(bhs * 64 + row) * 2048 + j0 + c8];
    }
    float pvv[4][4];
#pragma unroll
    for (int nt = 0; nt < 4; ++nt) {
      const int j = j0 + nt * 16 + lm;
#pragma unroll
      for (int r = 0; r < 4; ++r) {
        const int i = iw + lq * 4 + r;
        // rel-shift: ps[i, 2047-i+j] if j<=i ; 0 if j==i+1 ; ps[i+1, j-i-2] if j>=i+2
        float pv = 0.f;
        if (j <= i)          pv = bf2f(psb[(size_t)i * 2048 + (2047 - i + j)]);
        else if (j >= i + 2) pv = bf2f(psb[(size_t)(i + 1) * 2048 + (j - i - 2)]);
        pvv[nt][r] = pv;
      }
    }
    __syncthreads();
#pragma unroll
    for (int s = 0; s < 2; ++s) {
      int u = tid + s * 256, row = u >> 3, c8 = (u & 7) * 8;
      *(uint4*)&Ks[row][c8] = kr[s];
      *(uint4*)&Vs[row][c8] = vr[s];
    }
    __syncthreads();
    float lgt[4][4];
#pragma unroll
    for (int nt = 0; nt < 4; ++nt) {
      bf16x8 b0 = *(const bf16x8*)&Ks[nt * 16 + lm][lq * 8];
      bf16x8 b1 = *(const bf16x8*)&Ks[nt * 16 + lm][32 + lq * 8];
      f32x4 c = __builtin_amdgcn_mfma_f32_16x16x32_bf16(au0, b0, (f32x4){0.f,0.f,0.f,0.f}, 0, 0, 0);
      c = __builtin_amdgcn_mfma_f32_16x16x32_bf16(au1, b1, c, 0, 0, 0);
#pragma unroll
      for (int r = 0; r < 4; ++r) lgt[nt][r] = (c[r] + pvv[nt][r]) * 0.125f;
    }
#pragma unroll
    for (int r = 0; r < 4; ++r) {
      float rmax = fmaxf(fmaxf(lgt[0][r], lgt[1][r]), fmaxf(lgt[2][r], lgt[3][r]));
#pragma unroll
      for (int off = 1; off < 16; off <<= 1) rmax = fmaxf(rmax, __shfl_xor(rmax, off, 64));
      const float mnew = fmaxf(m_run[r], rmax);
      const float alpha = exp2f((m_run[r] - mnew) * 1.4426950408889634f);
      float p[4], psum = 0.f;
#pragma unroll
      for (int nt = 0; nt < 4; ++nt) {
        p[nt] = exp2f((lgt[nt][r] - mnew) * 1.4426950408889634f);
        psum += p[nt];
      }
#pragma unroll
      for (int off = 1; off < 16; off <<= 1) psum += __shfl_xor(psum, off, 64);
      l_run[r] = l_run[r] * alpha + psum;
      m_run[r] = mnew;
#pragma unroll
      for (int dt = 0; dt < 4; ++dt) oacc[dt][r] *= alpha;
#pragma unroll
      for (int nt = 0; nt < 4; ++nt) Ps[w][lq * 4 + r][nt * 16 + lm] = (short)f2bf(p[nt]);
    }
    // P: C-layout -> A-layout via per-wave LDS (same wave, in-order DS pipe)
    bf16x8 p0 = *(const bf16x8*)&Ps[w][lm][lq * 8];
    bf16x8 p1 = *(const bf16x8*)&Ps[w][lm][32 + lq * 8];
#pragma unroll
    for (int dt = 0; dt < 4; ++dt) {
      bf16x8 v0 = *(const bf16x8*)&Vs[dt * 16 + lm][lq * 8];
      bf16x8 v1 = *(const bf16x8*)&Vs[dt * 16 + lm][32 + lq * 8];
      oacc[dt] = __builtin_amdgcn_mfma_f32_16x16x32_bf16(p0, v0, oacc[dt], 0, 0, 0);
      oacc[dt] = __builtin_amdgcn_mfma_f32_16x16x32_bf16(p1, v1, oacc[dt], 0, 0, 0);
    }
  }
  const size_t orow = (size_t)(chunk * 16 + bh) * 2048;
#pragma unroll
  for (int r = 0; r < 4; ++r) {
    const int i = iw + lq * 4 + r;
#pragma unroll
    for (int dt = 0; dt < 4; ++dt)
      opart[(orow + i) * 64 + dt * 16 + lm] = oacc[dt][r];
    if (lm == 0) {
      ml[(orow + i) * 2]     = m_run[r];
      ml[(orow + i) * 2 + 1] = l_run[r];
    }
  }
}

// Merge the 2 KV-chunk partials -> og bf16 [B,N,H*HD]
__global__ __launch_bounds__(256) void k_combine(const float* __restrict__ opart,
    const float* __restrict__ ml, unsigned short* __restrict__ og) {
  const int row = blockIdx.x * 4 + (threadIdx.x >> 6);  // bh*2048 + i, 32768 rows
  const int d = threadIdx.x & 63;
  const float m1 = ml[(size_t)row * 2],           l1 = ml[(size_t)row * 2 + 1];
  const float m2 = ml[(size_t)(32768 + row) * 2], l2 = ml[(size_t)(32768 + row) * 2 + 1];
  const float mm = fmaxf(m1, m2);
  const float a1 = exp2f((m1 - mm) * 1.4426950408889634f);
  const float a2 = exp2f((m2 - mm) * 1.4426950408889634f);
  const float inv = 1.f / (a1 * l1 + a2 * l2);
  const float o = (a1 * opart[(size_t)row * 64 + d] +
                   a2 * opart[(size_t)(32768 + row) * 64 + d]) * inv;
  const int bh = row >> 11, i = row & 2047, b = bh >> 3, h = bh & 7;
  og[((size_t)(b * 2048 + i)) * 512 + h * 64 + d] = f2bf(o);
}

// out = O @ Wproj^T + bproj   (og bf16, wproj/bproj/out fp32)
__global__ __launch_bounds__(256) void k_gemm_proj(const unsigned short* __restrict__ og,
    const float* __restrict__ wproj, const float* __restrict__ bproj,
    float* __restrict__ out) {
  __shared__ short As[64][72], Ws[64][72];
  f32x4 acc[4];
  const int m0 = blockIdx.y * 64, cc0 = blockIdx.x * 64;
  gemm_mainloop<512>(og + (size_t)m0 * 512, wproj + (size_t)cc0 * 512, As, Ws, acc);
  const int tid = threadIdx.x, w = tid >> 6, lane = tid & 63, lm = lane & 15, lq = lane >> 4;
#pragma unroll
  for (int nt = 0; nt < 4; ++nt) {
    const int cc = cc0 + nt * 16 + lm;
    const float bias = bproj[cc];
#pragma unroll
    for (int r = 0; r < 4; ++r) {
      const int m = m0 + w * 16 + lq * 4 + r;
      out[(size_t)m * 512 + cc] = acc[nt][r] + bias;
    }
  }
}

extern "C" void kernel_launch(void* const* d_in, const int* in_sizes, int n_in,
                              void* d_out, int out_size, void* d_ws, size_t ws_size,
                              hipStream_t stream) {
  const float* x     = (const float*)d_in[0];
  const float* pe    = (const float*)d_in[1];
  const float* wqkv  = (const float*)d_in[2];
  const float* wpos  = (const float*)d_in[3];
  const float* ub    = (const float*)d_in[4];
  const float* vb    = (const float*)d_in[5];
  const float* wproj = (const float*)d_in[6];
  const float* bproj = (const float*)d_in[7];
  float* out = (float*)d_out;
  unsigned short* ws = (unsigned short*)d_ws;

  const size_t SZ = (size_t)2 * 8 * 2048 * 64;  // one [B,H,N,HD] buffer (2M elems)
  unsigned short* qu  = ws;
  unsigned short* qv  = qu + SZ;
  unsigned short* kg  = qv + SZ;
  unsigned short* vg  = kg + SZ;
  unsigned short* vt  = vg + SZ;
  unsigned short* pos = vt + SZ;
  unsigned short* og  = pos + SZ;
  unsigned short* ps  = og + SZ;                       // [16, 2048, 2048] bf16 (128 MB)
  float* opart = (float*)(ps + (size_t)16 * 2048 * 2048);  // [2][16][2048][64] fp32 (16 MB)
  float* ml    = opart + (size_t)2 * 16 * 2048 * 64;       // [2][16][2048][2]  fp32 (0.5 MB)

  dim3 blk(256);
  hipLaunchKernelGGL(k_gemm_qkv,   dim3(24, 64),    blk, 0, stream, x, wqkv, ub, vb, qu, qv, kg, vg);
  hipLaunchKernelGGL(k_gemm_pos,   dim3(8, 64),     blk, 0, stream, pe, wpos, pos);
  hipLaunchKernelGGL(k_transpose_v,dim3(32, 16),    blk, 0, stream, vg, vt);
  hipLaunchKernelGGL(k_gemm_ps,    dim3(8, 32, 16), blk, 0, stream, qv, pos, ps);
  hipLaunchKernelGGL(k_flash,      dim3(32, 2, 16), blk, 0, stream, qu, kg, vt, ps, opart, ml);
  hipLaunchKernelGGL(k_combine,    dim3(8192),      blk, 0, stream, opart, ml, og);
  hipLaunchKernelGGL(k_gemm_proj,  dim3(8, 64),     blk, 0, stream, og, wproj, bproj, out);
}

// Round 6
// 300.075 us; speedup vs baseline: 1.4664x; 1.4664x over previous
//
#include <hip/hip_runtime.h>

// Problem constants: B=2, N=2048, C=512, H=8, HD=64
// Inputs fp32 (per reference); intermediates bf16 in ws; output fp32.
typedef __attribute__((ext_vector_type(8))) short bf16x8;
typedef __attribute__((ext_vector_type(4))) float f32x4;

__device__ __forceinline__ float bf2f(unsigned short u) {
  union { unsigned int i; float f; } c; c.i = ((unsigned int)u) << 16; return c.f;
}
__device__ __forceinline__ unsigned short f2bf(float x) {
  union { float f; unsigned int i; } c; c.f = x;
  return (unsigned short)((c.i + 0x7fffu + ((c.i >> 16) & 1u)) >> 16);
}

// Load 8 source elements as 8 packed bf16 (one uint4).
template <typename T> __device__ __forceinline__ uint4 ld8(const T* p);
template <> __device__ __forceinline__ uint4 ld8<unsigned short>(const unsigned short* p) {
  return *(const uint4*)p;
}
template <> __device__ __forceinline__ uint4 ld8<float>(const float* p) {
  const float4 a = *(const float4*)p;
  const float4 b = *(const float4*)(p + 4);
  uint4 r;
  r.x = (unsigned)f2bf(a.x) | ((unsigned)f2bf(a.y) << 16);
  r.y = (unsigned)f2bf(a.z) | ((unsigned)f2bf(a.w) << 16);
  r.z = (unsigned)f2bf(b.x) | ((unsigned)f2bf(b.y) << 16);
  r.w = (unsigned)f2bf(b.z) | ((unsigned)f2bf(b.w) << 16);
  return r;
}

// 64x64 output tile, 256 threads (4 waves x 16-row strips), NT GEMM:
// acc[nt][r] = C[m0 + w*16 + lq*4 + r][cc0 + nt*16 + lm]
template <int K, typename TA, typename TW>
__device__ __forceinline__ void gemm_mainloop(const TA* __restrict__ Arow,
                                              const TW* __restrict__ Wrow,
                                              short (*As)[72], short (*Ws)[72], f32x4 acc[4]) {
  const int tid = threadIdx.x;
  const int w = tid >> 6, lane = tid & 63, lm = lane & 15, lq = lane >> 4;
#pragma unroll
  for (int nt = 0; nt < 4; ++nt) acc[nt] = (f32x4){0.f, 0.f, 0.f, 0.f};
#pragma unroll 1
  for (int kc = 0; kc < K; kc += 64) {
    __syncthreads();
#pragma unroll
    for (int s = 0; s < 2; ++s) {
      int u = tid + s * 256, row = u >> 3, c8 = (u & 7) * 8;
      *(uint4*)&As[row][c8] = ld8(&Arow[(size_t)row * K + kc + c8]);
      *(uint4*)&Ws[row][c8] = ld8(&Wrow[(size_t)row * K + kc + c8]);
    }
    __syncthreads();
#pragma unroll
    for (int kk = 0; kk < 64; kk += 32) {
      bf16x8 a = *(const bf16x8*)&As[w * 16 + lm][kk + lq * 8];
#pragma unroll
      for (int nt = 0; nt < 4; ++nt) {
        bf16x8 bb = *(const bf16x8*)&Ws[nt * 16 + lm][kk + lq * 8];
        acc[nt] = __builtin_amdgcn_mfma_f32_16x16x32_bf16(a, bb, acc[nt], 0, 0, 0);
      }
    }
  }
}

// qkv = x @ Wqkv^T; scatter to qu=q+u_bias, qv=q+v_bias, k, v in [B,H,N,HD] (bf16)
__global__ __launch_bounds__(256) void k_gemm_qkv(const float* __restrict__ x,
    const float* __restrict__ wqkv, const float* __restrict__ ub,
    const float* __restrict__ vb, unsigned short* __restrict__ qu,
    unsigned short* __restrict__ qv, unsigned short* __restrict__ kg,
    unsigned short* __restrict__ vg) {
  __shared__ short As[64][72], Ws[64][72];
  f32x4 acc[4];
  const int m0 = blockIdx.y * 64, cc0 = blockIdx.x * 64;
  gemm_mainloop<512>(x + (size_t)m0 * 512, wqkv + (size_t)cc0 * 512, As, Ws, acc);
  const int tid = threadIdx.x, w = tid >> 6, lane = tid & 63, lm = lane & 15, lq = lane >> 4;
#pragma unroll
  for (int nt = 0; nt < 4; ++nt) {
    const int cc = cc0 + nt * 16 + lm;
    const int sec = cc >> 9, rem = cc & 511, h = rem >> 6, d = rem & 63;
#pragma unroll
    for (int r = 0; r < 4; ++r) {
      const int m = m0 + w * 16 + lq * 4 + r;
      const int b = m >> 11, n = m & 2047;
      const size_t idx = ((size_t)(b * 8 + h) * 2048 + n) * 64 + d;
      const float val = acc[nt][r];
      if (sec == 0) {
        qu[idx] = f2bf(val + ub[rem]);
        qv[idx] = f2bf(val + vb[rem]);
      } else if (sec == 1) {
        kg[idx] = f2bf(val);
      } else {
        vg[idx] = f2bf(val);
      }
    }
  }
}

// pos = pos_embedding @ Wpos^T -> [B,H,N,HD] (bf16)
__global__ __launch_bounds__(256) void k_gemm_pos(const float* __restrict__ pe,
    const float* __restrict__ wpos, unsigned short* __restrict__ pos) {
  __shared__ short As[64][72], Ws[64][72];
  f32x4 acc[4];
  const int m0 = blockIdx.y * 64, cc0 = blockIdx.x * 64;
  gemm_mainloop<512>(pe + (size_t)m0 * 512, wpos + (size_t)cc0 * 512, As, Ws, acc);
  const int tid = threadIdx.x, w = tid >> 6, lane = tid & 63, lm = lane & 15, lq = lane >> 4;
#pragma unroll
  for (int nt = 0; nt < 4; ++nt) {
    const int cc = cc0 + nt * 16 + lm, h = cc >> 6, d = cc & 63;
#pragma unroll
    for (int r = 0; r < 4; ++r) {
      const int m = m0 + w * 16 + lq * 4 + r, b = m >> 11, n = m & 2047;
      pos[((size_t)(b * 8 + h) * 2048 + n) * 64 + d] = f2bf(acc[nt][r]);
    }
  }
}

// vt[b,h,d,n] = v[b,h,n,d]
__global__ __launch_bounds__(256) void k_transpose_v(const unsigned short* __restrict__ vg,
                                                     unsigned short* __restrict__ vt) {
  __shared__ short T[64][72];
  const int tid = threadIdx.x, bhid = blockIdx.y, n0 = blockIdx.x * 64;
#pragma unroll
  for (int s = 0; s < 2; ++s) {
    int u = tid + s * 256, row = u >> 3, c8 = (u & 7) * 8;
    *(uint4*)&T[row][c8] = *(const uint4*)&vg[((size_t)bhid * 2048 + n0 + row) * 64 + c8];
  }
  __syncthreads();
#pragma unroll
  for (int s = 0; s < 2; ++s) {
    int u = tid + s * 256, d = u >> 3, n8 = (u & 7) * 8;
    alignas(16) unsigned short tmp[8];
#pragma unroll
    for (int jj = 0; jj < 8; ++jj) tmp[jj] = (unsigned short)T[n8 + jj][d];
    *(uint4*)&vt[((size_t)bhid * 64 + d) * 2048 + n0 + n8] = *(const uint4*)tmp;
  }
}

// Fused flash attention with on-the-fly relative-position scores.
// Per j-tile: stage K(64), V(64), pos-window(128 rows); compute the diagonal
// ps band T[t][s] = qv[i0+t].pos[(pb+s)&2047] via MFMA into LDS with
// NON-ALIASING row stride 136 (write t*136+s, read rr*135+64+g — every slot
// has a unique writer; the R5 skew-69 layout raced across strip boundaries);
// gather shifted scores from LDS; online softmax; P@V.
__global__ __launch_bounds__(256) void k_flash(const unsigned short* __restrict__ qu,
    const unsigned short* __restrict__ qv, const unsigned short* __restrict__ kg,
    const unsigned short* __restrict__ vt, const unsigned short* __restrict__ posg,
    unsigned short* __restrict__ og) {
  __shared__ short Ks[64][72], Vs[64][72], Pn[128][72], Ps[4][16][72];
  __shared__ short Tl[65 * 136];  // 17680 B; rows 0..64, cols s in [0,128)
  const int tid = threadIdx.x, w = tid >> 6, lane = tid & 63, lm = lane & 15, lq = lane >> 4;
  const int bh = blockIdx.y, i0 = blockIdx.x * 64;
  const int iw = i0 + w * 16;
  const size_t bhs = (size_t)bh;
  const unsigned short* qub = qu + bhs * 2048 * 64;
  const unsigned short* qvb = qv + bhs * 2048 * 64;
  const unsigned short* pob = posg + bhs * 2048 * 64;
  // Preloaded A-frags (j-independent): content (qu), strip (qv), extra strip (qv rows i0+49..)
  const bf16x8 au0 = *(const bf16x8*)&qub[(size_t)(iw + lm) * 64 + lq * 8];
  const bf16x8 au1 = *(const bf16x8*)&qub[(size_t)(iw + lm) * 64 + 32 + lq * 8];
  const bf16x8 av0 = *(const bf16x8*)&qvb[(size_t)(iw + lm) * 64 + lq * 8];
  const bf16x8 av1 = *(const bf16x8*)&qvb[(size_t)(iw + lm) * 64 + 32 + lq * 8];
  const int rowe = min(i0 + 49 + lm, 2047);  // row 64 never read when i0==1984 (clamp safe)
  const bf16x8 ae0 = *(const bf16x8*)&qvb[(size_t)rowe * 64 + lq * 8];
  const bf16x8 ae1 = *(const bf16x8*)&qvb[(size_t)rowe * 64 + 32 + lq * 8];
  float m_run[4], l_run[4];
  f32x4 oacc[4];
#pragma unroll
  for (int r = 0; r < 4; ++r) { m_run[r] = -1e30f; l_run[r] = 0.f; }
#pragma unroll
  for (int dt = 0; dt < 4; ++dt) oacc[dt] = (f32x4){0.f, 0.f, 0.f, 0.f};
  const int krow = tid >> 3, kc8 = (tid & 7) * 8;  // staging coords for K/V (512 chunks)
#pragma unroll 1
  for (int j0 = 0; j0 < 2048; j0 += 64) {
    // ---- prefetch global -> regs (before barrier) ----
    uint4 kr0 = *(const uint4*)&kg[(bhs * 2048 + j0 + krow) * 64 + kc8];
    uint4 kr1 = *(const uint4*)&kg[(bhs * 2048 + j0 + krow + 32) * 64 + kc8];
    uint4 vr0 = *(const uint4*)&vt[(bhs * 64 + krow) * 2048 + j0 + kc8];
    uint4 vr1 = *(const uint4*)&vt[(bhs * 64 + krow + 32) * 2048 + j0 + kc8];
    const int pb = 1983 - i0 + j0;
    uint4 pr[4];
#pragma unroll
    for (int s = 0; s < 4; ++s) {
      int u = tid + s * 256, prow = u >> 3, c8 = (u & 7) * 8;
      int grow = (pb + prow + 4096) & 2047;
      pr[s] = *(const uint4*)&pob[(size_t)grow * 64 + c8];
    }
    __syncthreads();  // S1: prior step's LDS reads complete
    *(uint4*)&Ks[krow][kc8] = kr0;
    *(uint4*)&Ks[krow + 32][kc8] = kr1;
    *(uint4*)&Vs[krow][kc8] = vr0;
    *(uint4*)&Vs[krow + 32][kc8] = vr1;
#pragma unroll
    for (int s = 0; s < 4; ++s) {
      int u = tid + s * 256, prow = u >> 3, c8 = (u & 7) * 8;
      *(uint4*)&Pn[prow][c8] = pr[s];
    }
    __syncthreads();  // S2: staging visible
    // ---- T band: strip w = rows [w*16, w*16+16), col-tiles ct = 3-w .. 7-w ----
#pragma unroll
    for (int c = 0; c < 5; ++c) {
      const int ct = 3 - w + c;
      bf16x8 b0 = *(const bf16x8*)&Pn[ct * 16 + lm][lq * 8];
      bf16x8 b1 = *(const bf16x8*)&Pn[ct * 16 + lm][32 + lq * 8];
      f32x4 tacc = __builtin_amdgcn_mfma_f32_16x16x32_bf16(av0, b0, (f32x4){0.f,0.f,0.f,0.f}, 0, 0, 0);
      tacc = __builtin_amdgcn_mfma_f32_16x16x32_bf16(av1, b1, tacc, 0, 0, 0);
#pragma unroll
      for (int r = 0; r < 4; ++r)
        Tl[(w * 16 + lq * 4 + r) * 136 + ct * 16 + lm] = (short)f2bf(tacc[r]);
    }
    // extra strip (rows i0+49..i0+64): wave w does col-tile ct=w; keep only row t=64
    {
      bf16x8 b0 = *(const bf16x8*)&Pn[w * 16 + lm][lq * 8];
      bf16x8 b1 = *(const bf16x8*)&Pn[w * 16 + lm][32 + lq * 8];
      f32x4 eacc = __builtin_amdgcn_mfma_f32_16x16x32_bf16(ae0, b0, (f32x4){0.f,0.f,0.f,0.f}, 0, 0, 0);
      eacc = __builtin_amdgcn_mfma_f32_16x16x32_bf16(ae1, b1, eacc, 0, 0, 0);
      if (lq == 3) Tl[64 * 136 + w * 16 + lm] = (short)f2bf(eacc[3]);  // m=15 -> t=64
    }
    // ---- content QK^T ----
    f32x4 cacc[4];
#pragma unroll
    for (int nt = 0; nt < 4; ++nt) {
      bf16x8 b0 = *(const bf16x8*)&Ks[nt * 16 + lm][lq * 8];
      bf16x8 b1 = *(const bf16x8*)&Ks[nt * 16 + lm][32 + lq * 8];
      cacc[nt] = __builtin_amdgcn_mfma_f32_16x16x32_bf16(au0, b0, (f32x4){0.f,0.f,0.f,0.f}, 0, 0, 0);
      cacc[nt] = __builtin_amdgcn_mfma_f32_16x16x32_bf16(au1, b1, cacc[nt], 0, 0, 0);
    }
    __syncthreads();  // S3: Tl visible (cross-wave rows)
    // ---- gather shifted ps from Tl + logits ----
    // shifted[i][j]: rr=t (j<=i), 0 (j==i+1), rr=t+1 (j>=i+2); slot (rr, 64+g-rr)
    float lgt[4][4];
#pragma unroll
    for (int nt = 0; nt < 4; ++nt) {
      const int j = j0 + nt * 16 + lm, g = nt * 16 + lm;
#pragma unroll
      for (int r = 0; r < 4; ++r) {
        const int i = iw + lq * 4 + r, t = i - i0;
        float pv;
        if (j <= i)          pv = bf2f((unsigned short)Tl[t * 135 + 64 + g]);
        else if (j == i + 1) pv = 0.f;
        else                 pv = bf2f((unsigned short)Tl[(t + 1) * 135 + 64 + g]);
        lgt[nt][r] = (cacc[nt][r] + pv) * 0.125f;
      }
    }
    // ---- online softmax ----
#pragma unroll
    for (int r = 0; r < 4; ++r) {
      float rmax = fmaxf(fmaxf(lgt[0][r], lgt[1][r]), fmaxf(lgt[2][r], lgt[3][r]));
#pragma unroll
      for (int off = 1; off < 16; off <<= 1) rmax = fmaxf(rmax, __shfl_xor(rmax, off, 64));
      const float mnew = fmaxf(m_run[r], rmax);
      const float alpha = exp2f((m_run[r] - mnew) * 1.4426950408889634f);
      float p[4], psum = 0.f;
#pragma unroll
      for (int nt = 0; nt < 4; ++nt) {
        p[nt] = exp2f((lgt[nt][r] - mnew) * 1.4426950408889634f);
        psum += p[nt];
      }
#pragma unroll
      for (int off = 1; off < 16; off <<= 1) psum += __shfl_xor(psum, off, 64);
      l_run[r] = l_run[r] * alpha + psum;
      m_run[r] = mnew;
#pragma unroll
      for (int dt = 0; dt < 4; ++dt) oacc[dt][r] *= alpha;
#pragma unroll
      for (int nt = 0; nt < 4; ++nt) Ps[w][lq * 4 + r][nt * 16 + lm] = (short)f2bf(p[nt]);
    }
    // ---- P@V (P: C-layout -> A-layout via per-wave LDS, in-order DS) ----
    bf16x8 p0 = *(const bf16x8*)&Ps[w][lm][lq * 8];
    bf16x8 p1 = *(const bf16x8*)&Ps[w][lm][32 + lq * 8];
#pragma unroll
    for (int dt = 0; dt < 4; ++dt) {
      bf16x8 v0 = *(const bf16x8*)&Vs[dt * 16 + lm][lq * 8];
      bf16x8 v1 = *(const bf16x8*)&Vs[dt * 16 + lm][32 + lq * 8];
      oacc[dt] = __builtin_amdgcn_mfma_f32_16x16x32_bf16(p0, v0, oacc[dt], 0, 0, 0);
      oacc[dt] = __builtin_amdgcn_mfma_f32_16x16x32_bf16(p1, v1, oacc[dt], 0, 0, 0);
    }
  }
  const int b = bh >> 3, h = bh & 7;
#pragma unroll
  for (int r = 0; r < 4; ++r) {
    const float inv = 1.f / l_run[r];
    const int i = iw + lq * 4 + r;
#pragma unroll
    for (int dt = 0; dt < 4; ++dt)
      og[((size_t)b * 2048 + i) * 512 + h * 64 + dt * 16 + lm] = f2bf(oacc[dt][r] * inv);
  }
}

// out = O @ Wproj^T + bproj   (og bf16, wproj/bproj/out fp32)
__global__ __launch_bounds__(256) void k_gemm_proj(const unsigned short* __restrict__ og,
    const float* __restrict__ wproj, const float* __restrict__ bproj,
    float* __restrict__ out) {
  __shared__ short As[64][72], Ws[64][72];
  f32x4 acc[4];
  const int m0 = blockIdx.y * 64, cc0 = blockIdx.x * 64;
  gemm_mainloop<512>(og + (size_t)m0 * 512, wproj + (size_t)cc0 * 512, As, Ws, acc);
  const int tid = threadIdx.x, w = tid >> 6, lane = tid & 63, lm = lane & 15, lq = lane >> 4;
#pragma unroll
  for (int nt = 0; nt < 4; ++nt) {
    const int cc = cc0 + nt * 16 + lm;
    const float bias = bproj[cc];
#pragma unroll
    for (int r = 0; r < 4; ++r) {
      const int m = m0 + w * 16 + lq * 4 + r;
      out[(size_t)m * 512 + cc] = acc[nt][r] + bias;
    }
  }
}

extern "C" void kernel_launch(void* const* d_in, const int* in_sizes, int n_in,
                              void* d_out, int out_size, void* d_ws, size_t ws_size,
                              hipStream_t stream) {
  const float* x     = (const float*)d_in[0];
  const float* pe    = (const float*)d_in[1];
  const float* wqkv  = (const float*)d_in[2];
  const float* wpos  = (const float*)d_in[3];
  const float* ub    = (const float*)d_in[4];
  const float* vb    = (const float*)d_in[5];
  const float* wproj = (const float*)d_in[6];
  const float* bproj = (const float*)d_in[7];
  float* out = (float*)d_out;
  unsigned short* ws = (unsigned short*)d_ws;

  const size_t SZ = (size_t)2 * 8 * 2048 * 64;  // one [B,H,N,HD] buffer (2M elems)
  unsigned short* qu  = ws;
  unsigned short* qv  = qu + SZ;
  unsigned short* kg  = qv + SZ;
  unsigned short* vg  = kg + SZ;
  unsigned short* vt  = vg + SZ;
  unsigned short* pos = vt + SZ;
  unsigned short* og  = pos + SZ;

  dim3 blk(256);
  hipLaunchKernelGGL(k_gemm_qkv,   dim3(24, 64), blk, 0, stream, x, wqkv, ub, vb, qu, qv, kg, vg);
  hipLaunchKernelGGL(k_gemm_pos,   dim3(8, 64),  blk, 0, stream, pe, wpos, pos);
  hipLaunchKernelGGL(k_transpose_v,dim3(32, 16), blk, 0, stream, vg, vt);
  hipLaunchKernelGGL(k_flash,      dim3(32, 16), blk, 0, stream, qu, qv, kg, vt, pos, og);
  hipLaunchKernelGGL(k_gemm_proj,  dim3(8, 64),  blk, 0, stream, og, wproj, bproj, out);
}

// Round 7
// 288.527 us; speedup vs baseline: 1.5251x; 1.0400x over previous
//
#include <hip/hip_runtime.h>

// Problem constants: B=2, N=2048, C=512, H=8, HD=64
// Inputs fp32 (per reference); intermediates bf16 in ws; output fp32.
typedef __attribute__((ext_vector_type(8))) short bf16x8;
typedef __attribute__((ext_vector_type(4))) float f32x4;

__device__ __forceinline__ float bf2f(unsigned short u) {
  union { unsigned int i; float f; } c; c.i = ((unsigned int)u) << 16; return c.f;
}
__device__ __forceinline__ unsigned short f2bf(float x) {
  union { float f; unsigned int i; } c; c.f = x;
  return (unsigned short)((c.i + 0x7fffu + ((c.i >> 16) & 1u)) >> 16);
}

// Load 8 source elements as 8 packed bf16 (one uint4).
template <typename T> __device__ __forceinline__ uint4 ld8(const T* p);
template <> __device__ __forceinline__ uint4 ld8<unsigned short>(const unsigned short* p) {
  return *(const uint4*)p;
}
template <> __device__ __forceinline__ uint4 ld8<float>(const float* p) {
  const float4 a = *(const float4*)p;
  const float4 b = *(const float4*)(p + 4);
  uint4 r;
  r.x = (unsigned)f2bf(a.x) | ((unsigned)f2bf(a.y) << 16);
  r.y = (unsigned)f2bf(a.z) | ((unsigned)f2bf(a.w) << 16);
  r.z = (unsigned)f2bf(b.x) | ((unsigned)f2bf(b.y) << 16);
  r.w = (unsigned)f2bf(b.z) | ((unsigned)f2bf(b.w) << 16);
  return r;
}

// 64x64 output tile, 256 threads (4 waves x 16-row strips), NT GEMM:
// acc[nt][r] = C[m0 + w*16 + lq*4 + r][cc0 + nt*16 + lm]
template <int K, typename TA, typename TW>
__device__ __forceinline__ void gemm_mainloop(const TA* __restrict__ Arow,
                                              const TW* __restrict__ Wrow,
                                              short (*As)[72], short (*Ws)[72], f32x4 acc[4]) {
  const int tid = threadIdx.x;
  const int w = tid >> 6, lane = tid & 63, lm = lane & 15, lq = lane >> 4;
#pragma unroll
  for (int nt = 0; nt < 4; ++nt) acc[nt] = (f32x4){0.f, 0.f, 0.f, 0.f};
#pragma unroll 1
  for (int kc = 0; kc < K; kc += 64) {
    __syncthreads();
#pragma unroll
    for (int s = 0; s < 2; ++s) {
      int u = tid + s * 256, row = u >> 3, c8 = (u & 7) * 8;
      *(uint4*)&As[row][c8] = ld8(&Arow[(size_t)row * K + kc + c8]);
      *(uint4*)&Ws[row][c8] = ld8(&Wrow[(size_t)row * K + kc + c8]);
    }
    __syncthreads();
#pragma unroll
    for (int kk = 0; kk < 64; kk += 32) {
      bf16x8 a = *(const bf16x8*)&As[w * 16 + lm][kk + lq * 8];
#pragma unroll
      for (int nt = 0; nt < 4; ++nt) {
        bf16x8 bb = *(const bf16x8*)&Ws[nt * 16 + lm][kk + lq * 8];
        acc[nt] = __builtin_amdgcn_mfma_f32_16x16x32_bf16(a, bb, acc[nt], 0, 0, 0);
      }
    }
  }
}

// qkv = x @ Wqkv^T; scatter to qu=q+u_bias, qv=q+v_bias, k, v in [B,H,N,HD] (bf16)
__global__ __launch_bounds__(256) void k_gemm_qkv(const float* __restrict__ x,
    const float* __restrict__ wqkv, const float* __restrict__ ub,
    const float* __restrict__ vb, unsigned short* __restrict__ qu,
    unsigned short* __restrict__ qv, unsigned short* __restrict__ kg,
    unsigned short* __restrict__ vg) {
  __shared__ short As[64][72], Ws[64][72];
  f32x4 acc[4];
  const int m0 = blockIdx.y * 64, cc0 = blockIdx.x * 64;
  gemm_mainloop<512>(x + (size_t)m0 * 512, wqkv + (size_t)cc0 * 512, As, Ws, acc);
  const int tid = threadIdx.x, w = tid >> 6, lane = tid & 63, lm = lane & 15, lq = lane >> 4;
#pragma unroll
  for (int nt = 0; nt < 4; ++nt) {
    const int cc = cc0 + nt * 16 + lm;
    const int sec = cc >> 9, rem = cc & 511, h = rem >> 6, d = rem & 63;
#pragma unroll
    for (int r = 0; r < 4; ++r) {
      const int m = m0 + w * 16 + lq * 4 + r;
      const int b = m >> 11, n = m & 2047;
      const size_t idx = ((size_t)(b * 8 + h) * 2048 + n) * 64 + d;
      const float val = acc[nt][r];
      if (sec == 0) {
        qu[idx] = f2bf(val + ub[rem]);
        qv[idx] = f2bf(val + vb[rem]);
      } else if (sec == 1) {
        kg[idx] = f2bf(val);
      } else {
        vg[idx] = f2bf(val);
      }
    }
  }
}

// pos = pos_embedding @ Wpos^T -> [B,H,N,HD] (bf16)
__global__ __launch_bounds__(256) void k_gemm_pos(const float* __restrict__ pe,
    const float* __restrict__ wpos, unsigned short* __restrict__ pos) {
  __shared__ short As[64][72], Ws[64][72];
  f32x4 acc[4];
  const int m0 = blockIdx.y * 64, cc0 = blockIdx.x * 64;
  gemm_mainloop<512>(pe + (size_t)m0 * 512, wpos + (size_t)cc0 * 512, As, Ws, acc);
  const int tid = threadIdx.x, w = tid >> 6, lane = tid & 63, lm = lane & 15, lq = lane >> 4;
#pragma unroll
  for (int nt = 0; nt < 4; ++nt) {
    const int cc = cc0 + nt * 16 + lm, h = cc >> 6, d = cc & 63;
#pragma unroll
    for (int r = 0; r < 4; ++r) {
      const int m = m0 + w * 16 + lq * 4 + r, b = m >> 11, n = m & 2047;
      pos[((size_t)(b * 8 + h) * 2048 + n) * 64 + d] = f2bf(acc[nt][r]);
    }
  }
}

// vt[b,h,d,n] = v[b,h,n,d]
__global__ __launch_bounds__(256) void k_transpose_v(const unsigned short* __restrict__ vg,
                                                     unsigned short* __restrict__ vt) {
  __shared__ short T[64][72];
  const int tid = threadIdx.x, bhid = blockIdx.y, n0 = blockIdx.x * 64;
#pragma unroll
  for (int s = 0; s < 2; ++s) {
    int u = tid + s * 256, row = u >> 3, c8 = (u & 7) * 8;
    *(uint4*)&T[row][c8] = *(const uint4*)&vg[((size_t)bhid * 2048 + n0 + row) * 64 + c8];
  }
  __syncthreads();
#pragma unroll
  for (int s = 0; s < 2; ++s) {
    int u = tid + s * 256, d = u >> 3, n8 = (u & 7) * 8;
    alignas(16) unsigned short tmp[8];
#pragma unroll
    for (int jj = 0; jj < 8; ++jj) tmp[jj] = (unsigned short)T[n8 + jj][d];
    *(uint4*)&vt[((size_t)bhid * 64 + d) * 2048 + n0 + n8] = *(const uint4*)tmp;
  }
}

// Fused flash attention, restructured for latency hiding:
//  - prefetch rotation: next tile's K/V/pos global loads issued after S2, held
//    in regs through the compute phase, ds_written after the next S1.
//  - circular 128-row pos window in LDS; only 64 new rows staged per iter.
//  - Tl band buffer at row stride 84 (write addr t*84 + s - 48 + 16*(t>>4);
//    row 64 at +16) -> unique writer per slot, lq-groups tile all 32 banks.
//    One read formula: Tl[rr*84 + 16 + g - (rr&15)], rr = t or t+1.
//  - Ps (P C->A transform) aliases the Ks region: Ks reads all complete
//    before S3, Ps writes start after S3, next Ks write guarded by S1.
// LDS total: (4608 + 4608 + 9216 + 5460) shorts = 47784 B -> 3 blocks/CU.
__global__ __launch_bounds__(256) void k_flash(const unsigned short* __restrict__ qu,
    const unsigned short* __restrict__ qv, const unsigned short* __restrict__ kg,
    const unsigned short* __restrict__ vt, const unsigned short* __restrict__ posg,
    unsigned short* __restrict__ og) {
  __shared__ short SB[23892];
  short* Ks = SB;            // 64 x stride 72  (aliased by Ps after S3)
  short* Vs = SB + 4608;     // 64 x stride 72
  short* Pn = SB + 9216;     // 128 x stride 72, circular pos window
  short* Tl = SB + 18432;    // 65 x stride 84 band buffer
  short* Ps = SB;            // alias of Ks
  const int tid = threadIdx.x, w = tid >> 6, lane = tid & 63, lm = lane & 15, lq = lane >> 4;
  const int bh = blockIdx.y, i0 = blockIdx.x * 64;
  const int iw = i0 + w * 16;
  const size_t bhs = (size_t)bh;
  const unsigned short* qub = qu + bhs * 2048 * 64;
  const unsigned short* qvb = qv + bhs * 2048 * 64;
  const unsigned short* pob = posg + bhs * 2048 * 64;
  // j-independent A-frags: content (qu), band strip (qv), extra strip (qv rows i0+49..i0+64)
  const bf16x8 au0 = *(const bf16x8*)&qub[(size_t)(iw + lm) * 64 + lq * 8];
  const bf16x8 au1 = *(const bf16x8*)&qub[(size_t)(iw + lm) * 64 + 32 + lq * 8];
  const bf16x8 av0 = *(const bf16x8*)&qvb[(size_t)(iw + lm) * 64 + lq * 8];
  const bf16x8 av1 = *(const bf16x8*)&qvb[(size_t)(iw + lm) * 64 + 32 + lq * 8];
  const int rowe = min(i0 + 49 + lm, 2047);  // row t=64 never read when i0==1984
  const bf16x8 ae0 = *(const bf16x8*)&qvb[(size_t)rowe * 64 + lq * 8];
  const bf16x8 ae1 = *(const bf16x8*)&qvb[(size_t)rowe * 64 + 32 + lq * 8];
  float m_run[4], l_run[4];
  f32x4 oacc[4];
#pragma unroll
  for (int r = 0; r < 4; ++r) { m_run[r] = -1e30f; l_run[r] = 0.f; }
#pragma unroll
  for (int dt = 0; dt < 4; ++dt) oacc[dt] = (f32x4){0.f, 0.f, 0.f, 0.f};
  const int krow = tid >> 3, kc8 = (tid & 7) * 8;
  const int pb0 = 1983 - i0;
  // ---- pre-loop prefetch for tile 0 ----
  uint4 kr0 = *(const uint4*)&kg[(bhs * 2048 + krow) * 64 + kc8];
  uint4 kr1 = *(const uint4*)&kg[(bhs * 2048 + krow + 32) * 64 + kc8];
  uint4 vr0 = *(const uint4*)&vt[(bhs * 64 + krow) * 2048 + kc8];
  uint4 vr1 = *(const uint4*)&vt[(bhs * 64 + krow + 32) * 2048 + kc8];
  uint4 pr[4];
#pragma unroll
  for (int s = 0; s < 4; ++s) {
    int u = tid + s * 256, prow = u >> 3, c8 = (u & 7) * 8;
    int grow = (pb0 + prow + 4096) & 2047;
    pr[s] = *(const uint4*)&pob[(size_t)grow * 64 + c8];
  }
#pragma unroll 1
  for (int jt = 0; jt < 32; ++jt) {
    const int j0 = jt * 64;
    const int pb = pb0 + j0;
    __syncthreads();  // S1: prior iteration's LDS reads (Ks/Ps, Vs, Pn, Tl) complete
    *(uint4*)&Ks[krow * 72 + kc8] = kr0;
    *(uint4*)&Ks[(krow + 32) * 72 + kc8] = kr1;
    *(uint4*)&Vs[krow * 72 + kc8] = vr0;
    *(uint4*)&Vs[(krow + 32) * 72 + kc8] = vr1;
    if (jt == 0) {
#pragma unroll
      for (int s = 0; s < 4; ++s) {
        int u = tid + s * 256, prow = u >> 3, c8 = (u & 7) * 8;
        int slot = (pb + prow) & 127;
        *(uint4*)&Pn[slot * 72 + c8] = pr[s];
      }
    } else {
#pragma unroll
      for (int s = 0; s < 2; ++s) {
        int u = tid + s * 256, prow = u >> 3, c8 = (u & 7) * 8;
        int slot = (pb + 64 + prow) & 127;  // rows [pb+64, pb+128) loaded last iter
        *(uint4*)&Pn[slot * 72 + c8] = pr[s];
      }
    }
    __syncthreads();  // S2: staging visible
    // ---- prefetch next tile (overlaps the whole compute phase) ----
    if (jt < 31) {
      const int jn = j0 + 64;
      kr0 = *(const uint4*)&kg[(bhs * 2048 + jn + krow) * 64 + kc8];
      kr1 = *(const uint4*)&kg[(bhs * 2048 + jn + krow + 32) * 64 + kc8];
      vr0 = *(const uint4*)&vt[(bhs * 64 + krow) * 2048 + jn + kc8];
      vr1 = *(const uint4*)&vt[(bhs * 64 + krow + 32) * 2048 + jn + kc8];
#pragma unroll
      for (int s = 0; s < 2; ++s) {
        int u = tid + s * 256, prow = u >> 3, c8 = (u & 7) * 8;
        int grow = (pb + 128 + prow + 4096) & 2047;
        pr[s] = *(const uint4*)&pob[(size_t)grow * 64 + c8];
      }
    }
    const int pbm = pb & 127;
    // ---- T band: strip w = rows [w*16, w*16+16), col-tiles ct = 3-w .. 7-w ----
    const int tbase = (w * 16 + lq * 4) * 84 + 16 * w - 48;
#pragma unroll
    for (int c = 0; c < 5; ++c) {
      const int ct = 3 - w + c;
      const int prow = (pbm + ct * 16 + lm) & 127;
      bf16x8 b0 = *(const bf16x8*)&Pn[prow * 72 + lq * 8];
      bf16x8 b1 = *(const bf16x8*)&Pn[prow * 72 + 32 + lq * 8];
      f32x4 tacc = __builtin_amdgcn_mfma_f32_16x16x32_bf16(av0, b0, (f32x4){0.f,0.f,0.f,0.f}, 0, 0, 0);
      tacc = __builtin_amdgcn_mfma_f32_16x16x32_bf16(av1, b1, tacc, 0, 0, 0);
#pragma unroll
      for (int r = 0; r < 4; ++r)
        Tl[tbase + r * 84 + ct * 16 + lm] = (short)f2bf(tacc[r]);
    }
    // extra strip: wave w computes col-tile ct=w of rows i0+49..i0+64; keep row t=64
    {
      const int prow = (pbm + w * 16 + lm) & 127;
      bf16x8 b0 = *(const bf16x8*)&Pn[prow * 72 + lq * 8];
      bf16x8 b1 = *(const bf16x8*)&Pn[prow * 72 + 32 + lq * 8];
      f32x4 eacc = __builtin_amdgcn_mfma_f32_16x16x32_bf16(ae0, b0, (f32x4){0.f,0.f,0.f,0.f}, 0, 0, 0);
      eacc = __builtin_amdgcn_mfma_f32_16x16x32_bf16(ae1, b1, eacc, 0, 0, 0);
      if (lq == 3) Tl[64 * 84 + 16 + w * 16 + lm] = (short)f2bf(eacc[3]);  // m=15 -> t=64
    }
    // ---- content QK^T (all Ks reads complete before S3) ----
    f32x4 cacc[4];
#pragma unroll
    for (int nt = 0; nt < 4; ++nt) {
      bf16x8 b0 = *(const bf16x8*)&Ks[(nt * 16 + lm) * 72 + lq * 8];
      bf16x8 b1 = *(const bf16x8*)&Ks[(nt * 16 + lm) * 72 + 32 + lq * 8];
      cacc[nt] = __builtin_amdgcn_mfma_f32_16x16x32_bf16(au0, b0, (f32x4){0.f,0.f,0.f,0.f}, 0, 0, 0);
      cacc[nt] = __builtin_amdgcn_mfma_f32_16x16x32_bf16(au1, b1, cacc[nt], 0, 0, 0);
    }
    __syncthreads();  // S3: Tl visible; Ks reads done chip-wide -> Ps alias safe
    // ---- gather shifted ps from Tl + logits ----
    float lgt[4][4];
#pragma unroll
    for (int nt = 0; nt < 4; ++nt) {
      const int j = j0 + nt * 16 + lm, g = nt * 16 + lm;
#pragma unroll
      for (int r = 0; r < 4; ++r) {
        const int i = iw + lq * 4 + r, t = i - i0;
        float pv;
        if (j == i + 1) {
          pv = 0.f;
        } else {
          const int rr = (j <= i) ? t : t + 1;
          pv = bf2f((unsigned short)Tl[rr * 84 + 16 + g - (rr & 15)]);
        }
        lgt[nt][r] = (cacc[nt][r] + pv) * 0.125f;
      }
    }
    // ---- online softmax ----
#pragma unroll
    for (int r = 0; r < 4; ++r) {
      float rmax = fmaxf(fmaxf(lgt[0][r], lgt[1][r]), fmaxf(lgt[2][r], lgt[3][r]));
#pragma unroll
      for (int off = 1; off < 16; off <<= 1) rmax = fmaxf(rmax, __shfl_xor(rmax, off, 64));
      const float mnew = fmaxf(m_run[r], rmax);
      const float alpha = exp2f((m_run[r] - mnew) * 1.4426950408889634f);
      float p[4], psum = 0.f;
#pragma unroll
      for (int nt = 0; nt < 4; ++nt) {
        p[nt] = exp2f((lgt[nt][r] - mnew) * 1.4426950408889634f);
        psum += p[nt];
      }
#pragma unroll
      for (int off = 1; off < 16; off <<= 1) psum += __shfl_xor(psum, off, 64);
      l_run[r] = l_run[r] * alpha + psum;
      m_run[r] = mnew;
#pragma unroll
      for (int dt = 0; dt < 4; ++dt) oacc[dt][r] *= alpha;
#pragma unroll
      for (int nt = 0; nt < 4; ++nt)
        Ps[w * 1152 + (lq * 4 + r) * 72 + nt * 16 + lm] = (short)f2bf(p[nt]);
    }
    // ---- P@V (P: C-layout -> A-layout via per-wave LDS, in-order DS) ----
    bf16x8 p0 = *(const bf16x8*)&Ps[w * 1152 + lm * 72 + lq * 8];
    bf16x8 p1 = *(const bf16x8*)&Ps[w * 1152 + lm * 72 + 32 + lq * 8];
#pragma unroll
    for (int dt = 0; dt < 4; ++dt) {
      bf16x8 v0 = *(const bf16x8*)&Vs[(dt * 16 + lm) * 72 + lq * 8];
      bf16x8 v1 = *(const bf16x8*)&Vs[(dt * 16 + lm) * 72 + 32 + lq * 8];
      oacc[dt] = __builtin_amdgcn_mfma_f32_16x16x32_bf16(p0, v0, oacc[dt], 0, 0, 0);
      oacc[dt] = __builtin_amdgcn_mfma_f32_16x16x32_bf16(p1, v1, oacc[dt], 0, 0, 0);
    }
  }
  const int b = bh >> 3, h = bh & 7;
#pragma unroll
  for (int r = 0; r < 4; ++r) {
    const float inv = 1.f / l_run[r];
    const int i = iw + lq * 4 + r;
#pragma unroll
    for (int dt = 0; dt < 4; ++dt)
      og[((size_t)b * 2048 + i) * 512 + h * 64 + dt * 16 + lm] = f2bf(oacc[dt][r] * inv);
  }
}

// out = O @ Wproj^T + bproj   (og bf16, wproj/bproj/out fp32)
__global__ __launch_bounds__(256) void k_gemm_proj(const unsigned short* __restrict__ og,
    const float* __restrict__ wproj, const float* __restrict__ bproj,
    float* __restrict__ out) {
  __shared__ short As[64][72], Ws[64][72];
  f32x4 acc[4];
  const int m0 = blockIdx.y * 64, cc0 = blockIdx.x * 64;
  gemm_mainloop<512>(og + (size_t)m0 * 512, wproj + (size_t)cc0 * 512, As, Ws, acc);
  const int tid = threadIdx.x, w = tid >> 6, lane = tid & 63, lm = lane & 15, lq = lane >> 4;
#pragma unroll
  for (int nt = 0; nt < 4; ++nt) {
    const int cc = cc0 + nt * 16 + lm;
    const float bias = bproj[cc];
#pragma unroll
    for (int r = 0; r < 4; ++r) {
      const int m = m0 + w * 16 + lq * 4 + r;
      out[(size_t)m * 512 + cc] = acc[nt][r] + bias;
    }
  }
}

extern "C" void kernel_launch(void* const* d_in, const int* in_sizes, int n_in,
                              void* d_out, int out_size, void* d_ws, size_t ws_size,
                              hipStream_t stream) {
  const float* x     = (const float*)d_in[0];
  const float* pe    = (const float*)d_in[1];
  const float* wqkv  = (const float*)d_in[2];
  const float* wpos  = (const float*)d_in[3];
  const float* ub    = (const float*)d_in[4];
  const float* vb    = (const float*)d_in[5];
  const float* wproj = (const float*)d_in[6];
  const float* bproj = (const float*)d_in[7];
  float* out = (float*)d_out;
  unsigned short* ws = (unsigned short*)d_ws;

  const size_t SZ = (size_t)2 * 8 * 2048 * 64;  // one [B,H,N,HD] buffer (2M elems)
  unsigned short* qu  = ws;
  unsigned short* qv  = qu + SZ;
  unsigned short* kg  = qv + SZ;
  unsigned short* vg  = kg + SZ;
  unsigned short* vt  = vg + SZ;
  unsigned short* pos = vt + SZ;
  unsigned short* og  = pos + SZ;

  dim3 blk(256);
  hipLaunchKernelGGL(k_gemm_qkv,   dim3(24, 64), blk, 0, stream, x, wqkv, ub, vb, qu, qv, kg, vg);
  hipLaunchKernelGGL(k_gemm_pos,   dim3(8, 64),  blk, 0, stream, pe, wpos, pos);
  hipLaunchKernelGGL(k_transpose_v,dim3(32, 16), blk, 0, stream, vg, vt);
  hipLaunchKernelGGL(k_flash,      dim3(32, 16), blk, 0, stream, qu, qv, kg, vt, pos, og);
  hipLaunchKernelGGL(k_gemm_proj,  dim3(8, 64),  blk, 0, stream, og, wproj, bproj, out);
}